// Round 1
// baseline (565.252 us; speedup 1.0000x reference)
//
#include <hip/hip_runtime.h>
#include <cstdint>
#include <climits>

static constexpr int DM   = 128;   // d_model
static constexpr int NH   = 8;
static constexpr int NP   = 4;
static constexpr int NCOL = NH * NP * 3;  // 96 off columns
static constexpr int NATT = NH * NP;      // 32 attn columns
static constexpr int VOXC = 8;

// ws int layout:
//  [0..2]  min_c,  [3..5] max_c,  [6] active count, [7] pad
//  [8 .. 8+n)      active point ids
//  [8+n .. 8+2n)   active mask bits (32 bits per point, bit t = h*NP+p)

__global__ void k_init(int* __restrict__ ws) {
  int t = threadIdx.x;
  if (t < 3) { ws[t] = INT_MAX; ws[3 + t] = INT_MIN; }
  if (t == 6) ws[6] = 0;
}

__global__ void k_minmax(const int* __restrict__ coords, int n, int* __restrict__ ws) {
  int mn[3] = {INT_MAX, INT_MAX, INT_MAX};
  int mx[3] = {INT_MIN, INT_MIN, INT_MIN};
  for (int i = blockIdx.x * blockDim.x + threadIdx.x; i < n; i += gridDim.x * blockDim.x) {
#pragma unroll
    for (int d = 0; d < 3; ++d) {
      int v = coords[i * 3 + d];
      mn[d] = min(mn[d], v);
      mx[d] = max(mx[d], v);
    }
  }
#pragma unroll
  for (int d = 0; d < 3; ++d) {
    for (int off = 32; off > 0; off >>= 1) {
      mn[d] = min(mn[d], __shfl_xor(mn[d], off, 64));
      mx[d] = max(mx[d], __shfl_xor(mx[d], off, 64));
    }
  }
  if ((threadIdx.x & 63) == 0) {
#pragma unroll
    for (int d = 0; d < 3; ++d) {
      atomicMin(&ws[d], mn[d]);
      atomicMax(&ws[3 + d], mx[d]);
    }
  }
}

// out rows default to b_out (inactive rows contribute zero before W_out).
__global__ void k_prefill(float* __restrict__ out, const float* __restrict__ bout, int n) {
  int i = blockIdx.x * blockDim.x + threadIdx.x;  // float4 index
  int total = n * (DM / 4);
  if (i >= total) return;
  reinterpret_cast<float4*>(out)[i] =
      reinterpret_cast<const float4*>(bout)[i & (DM / 4 - 1)];
}

// Per point: 96 off logits in fp32, mask bits; append active points to ws list.
__global__ __launch_bounds__(256) void k_mask(
    const float* __restrict__ q, const float* __restrict__ Woff,
    const float* __restrict__ boff, int n, int* __restrict__ ws) {
  int pt = blockIdx.x * blockDim.x + threadIdx.x;
  if (pt >= n) return;
  float rc[3];
#pragma unroll
  for (int d = 0; d < 3; ++d) rc[d] = (float)(ws[3 + d] - ws[d]);

  float acc[NCOL];
#pragma unroll
  for (int c = 0; c < NCOL; ++c) acc[c] = boff[c];

  const float4* q4 = reinterpret_cast<const float4*>(q + (size_t)pt * DM);
  for (int k4 = 0; k4 < DM / 4; ++k4) {
    float4 qv = q4[k4];
    float qs[4] = {qv.x, qv.y, qv.z, qv.w};
#pragma unroll
    for (int j = 0; j < 4; ++j) {
      const float* w = Woff + (size_t)(k4 * 4 + j) * NCOL;  // wave-uniform -> s_load
      float qk = qs[j];
#pragma unroll
      for (int c = 0; c < NCOL; ++c) acc[c] = fmaf(qk, w[c], acc[c]);
    }
  }

  unsigned int bits = 0u;
#pragma unroll
  for (int t = 0; t < NATT; ++t) {
    bool m = true;
#pragma unroll
    for (int j = 0; j < 3; ++j) {
      // reference: ((logit * range_c) / 2).astype(int32)  (trunc toward 0)
      float off = acc[t * 3 + j] * rc[j] * 0.5f;
      int oi = (int)off;
      m = m && (oi >= 0) && (oi < VOXC);
    }
    bits |= (m ? 1u : 0u) << t;
  }
  if (bits) {
    int pos = atomicAdd(&ws[6], 1);
    ws[8 + pos] = pt;
    ws[8 + n + pos] = (int)bits;
  }
}

// For each active point: attn softmax, lazy value row, epilogue GEMM row add.
__global__ __launch_bounds__(64) void k_active(
    const float* __restrict__ q, const float* __restrict__ vfea,
    const int* __restrict__ coords,
    const float* __restrict__ Wattn, const float* __restrict__ battn,
    const float* __restrict__ Wval, const float* __restrict__ bval,
    const float* __restrict__ Wout,
    float* __restrict__ out, int n, const int* __restrict__ ws) {
  const int lane = threadIdx.x;  // block = 1 wave (64)
  const int count = ws[6];
  const int mn0 = ws[0], mn1 = ws[1], mn2 = ws[2];
  const float rv0 = (float)((ws[3] - mn0) / VOXC + 1);
  const float rv1 = (float)((ws[4] - mn1) / VOXC + 1);

  for (int i = blockIdx.x; i < count; i += gridDim.x) {
    int pt = ws[8 + i];
    unsigned int bits = (unsigned int)ws[8 + n + i];

    // gather row: exact in fp32 (all terms multiples of 1/8, < 2^24)
    float i0 = (float)(coords[pt * 3 + 0] - mn0) * 0.125f;
    float i1 = (float)(coords[pt * 3 + 1] - mn1) * 0.125f;
    float i2 = (float)(coords[pt * 3 + 2] - mn2) * 0.125f;
    float flat = i0 * rv1 * rv0 + i1 * rv0 + i2;
    int g = (int)floorf(flat);
    g = min(max(g, 0), n - 1);

    const float* qrow = q + (size_t)pt * DM;

    // attn logits + softmax on lanes 0..31 (lane t = h*4+p), grouped by 4
    float w_h = 0.0f;
    if (lane < NATT) {
      float acc = battn[lane];
      for (int k = 0; k < DM; ++k) acc = fmaf(qrow[k], Wattn[k * NATT + lane], acc);
      float m = acc;
      m = fmaxf(m, __shfl_xor(m, 1, 4));
      m = fmaxf(m, __shfl_xor(m, 2, 4));
      float e = expf(acc - m);
      float s = e;
      s += __shfl_xor(s, 1, 4);
      s += __shfl_xor(s, 2, 4);
      float a = e / s;
      float am = ((bits >> lane) & 1u) ? a : 0.0f;
      float w = am;
      w += __shfl_xor(w, 1, 4);
      w += __shfl_xor(w, 2, 4);
      w_h = w;  // valid on all 4 lanes of each head group
    }

    // lazy value row g: lane handles dims (lane, lane+64)
    const float* vrow = vfea + (size_t)g * DM;
    float v0 = bval[lane], v1 = bval[lane + 64];
    for (int k = 0; k < DM; ++k) {
      float f = vrow[k];
      v0 = fmaf(f, Wval[k * DM + lane], v0);
      v1 = fmaf(f, Wval[k * DM + lane + 64], v1);
    }
    float wh0 = __shfl(w_h, (lane >> 4) * 4, 64);        // head of dim = lane
    float wh1 = __shfl(w_h, ((lane >> 4) + 4) * 4, 64);  // head of dim = lane+64
    float o0 = wh0 * v0;
    float o1 = wh1 * v1;

    // row epilogue: out[pt,:] += o @ W_out   (out already holds b_out)
    float s0 = 0.0f, s1 = 0.0f;
    for (int d = 0; d < 64; ++d) {
      float od = __shfl(o0, d, 64);
      s0 = fmaf(od, Wout[d * DM + lane], s0);
      s1 = fmaf(od, Wout[d * DM + lane + 64], s1);
    }
    for (int d = 0; d < 64; ++d) {
      float od = __shfl(o1, d, 64);
      s0 = fmaf(od, Wout[(d + 64) * DM + lane], s0);
      s1 = fmaf(od, Wout[(d + 64) * DM + lane + 64], s1);
    }
    out[(size_t)pt * DM + lane] += s0;
    out[(size_t)pt * DM + lane + 64] += s1;
  }
}

extern "C" void kernel_launch(void* const* d_in, const int* in_sizes, int n_in,
                              void* d_out, int out_size, void* d_ws, size_t ws_size,
                              hipStream_t stream) {
  const float* q     = (const float*)d_in[0];
  const float* vfea  = (const float*)d_in[1];
  const int*   coords= (const int*)d_in[2];
  const float* Woff  = (const float*)d_in[3];
  const float* boff  = (const float*)d_in[4];
  const float* Wattn = (const float*)d_in[5];
  const float* battn = (const float*)d_in[6];
  const float* Wval  = (const float*)d_in[7];
  const float* bval  = (const float*)d_in[8];
  const float* Wout  = (const float*)d_in[9];
  const float* bout  = (const float*)d_in[10];
  float* out = (float*)d_out;
  int n = in_sizes[0] / DM;
  int* ws = (int*)d_ws;

  k_init<<<1, 64, 0, stream>>>(ws);
  k_minmax<<<256, 256, 0, stream>>>(coords, n, ws);
  k_prefill<<<(n * (DM / 4) + 255) / 256, 256, 0, stream>>>(out, bout, n);
  k_mask<<<(n + 255) / 256, 256, 0, stream>>>(q, Woff, boff, n, ws);
  k_active<<<256, 64, 0, stream>>>(q, vfea, coords, Wattn, battn, Wval, bval, Wout, out, n, ws);
}

// Round 2
// 504.448 us; speedup vs baseline: 1.1205x; 1.1205x over previous
//
#include <hip/hip_runtime.h>
#include <cstdint>
#include <climits>

static constexpr int DM   = 128;   // d_model
static constexpr int NH   = 8;
static constexpr int NP   = 4;
static constexpr int NCOL = NH * NP * 3;  // 96 off columns
static constexpr int NATT = NH * NP;      // 32 attn columns
static constexpr int VOXC = 8;

// ws int layout:
//  [0..2]  min_c,  [3..5] max_c,  [6] active count, [7] pad
//  [8 .. 8+n)      active point ids
//  [8+n .. 8+2n)   active mask bits (32 bits per point, bit t = h*NP+p)

__global__ void k_init(int* __restrict__ ws) {
  int t = threadIdx.x;
  if (t < 3) { ws[t] = INT_MAX; ws[3 + t] = INT_MIN; }
  if (t == 6) ws[6] = 0;
}

__global__ __launch_bounds__(256) void k_minmax(const int* __restrict__ coords, int n,
                                                int* __restrict__ ws) {
  __shared__ int bmn[3], bmx[3];
  int t = threadIdx.x;
  if (t < 3) { bmn[t] = INT_MAX; bmx[t] = INT_MIN; }
  __syncthreads();

  int mn[3] = {INT_MAX, INT_MAX, INT_MAX};
  int mx[3] = {INT_MIN, INT_MIN, INT_MIN};
  for (int i = blockIdx.x * blockDim.x + t; i < n; i += gridDim.x * blockDim.x) {
#pragma unroll
    for (int d = 0; d < 3; ++d) {
      int v = coords[i * 3 + d];
      mn[d] = min(mn[d], v);
      mx[d] = max(mx[d], v);
    }
  }
#pragma unroll
  for (int d = 0; d < 3; ++d) {
    for (int off = 32; off > 0; off >>= 1) {
      mn[d] = min(mn[d], __shfl_xor(mn[d], off, 64));
      mx[d] = max(mx[d], __shfl_xor(mx[d], off, 64));
    }
  }
  if ((t & 63) == 0) {
#pragma unroll
    for (int d = 0; d < 3; ++d) {
      atomicMin(&bmn[d], mn[d]);
      atomicMax(&bmx[d], mx[d]);
    }
  }
  __syncthreads();
  if (t < 3) {
    atomicMin(&ws[t], bmn[t]);
    atomicMax(&ws[3 + t], bmx[t]);
  }
}

// Tiled fp32 GEMM (points x 96 cols) + mask bits + active-list append + b_out prefill.
// Block = 256 points; q staged through LDS (coalesced); Woff via wave-uniform scalar loads.
__global__ __launch_bounds__(256, 1) void k_mask(
    const float* __restrict__ q, const float* __restrict__ Woff,
    const float* __restrict__ boff, const float* __restrict__ bout,
    float* __restrict__ out, int n, int* __restrict__ ws) {
  constexpr int PTS = 256;
  constexpr int KT  = 32;
  constexpr int QS  = KT + 4;  // row stride in floats: 16B-aligned, breaks pow2 banks
  __shared__ float qs[PTS * QS];

  const int t    = threadIdx.x;
  const int base = blockIdx.x * PTS;
  const int pt   = base + t;

  float acc[NCOL];
#pragma unroll
  for (int c = 0; c < NCOL; ++c) acc[c] = boff[c];

  for (int kt = 0; kt < DM; kt += KT) {
    if (kt) __syncthreads();
    // stage 256 rows x KT floats: 2048 float4, 8 per thread, 128B-contiguous per 8 lanes
#pragma unroll
    for (int i = 0; i < 8; ++i) {
      int L   = t + i * 256;
      int row = L >> 3;    // 8 float4 per row
      int c4  = L & 7;
      int p   = base + row;
      float4 v = make_float4(0.f, 0.f, 0.f, 0.f);
      if (p < n) v = *reinterpret_cast<const float4*>(q + (size_t)p * DM + kt + c4 * 4);
      *reinterpret_cast<float4*>(&qs[row * QS + c4 * 4]) = v;
    }
    __syncthreads();

    const float* wb = Woff + (size_t)kt * NCOL;
#pragma unroll 2
    for (int k = 0; k < KT; ++k) {
      float qk = qs[t * QS + k];
      const float* w = wb + k * NCOL;  // wave-uniform -> s_load batches
#pragma unroll
      for (int c = 0; c < NCOL; ++c) acc[c] = fmaf(qk, w[c], acc[c]);
    }
  }

  // fused b_out prefill for this block's rows (coalesced float4 stores)
  {
    int rows = min(PTS, n - base);
    if (rows > 0) {
      int total4 = rows * (DM / 4);
      for (int L = t; L < total4; L += 256) {
        int row = L >> 5;  // 32 float4 per row
        int c4  = L & 31;
        *reinterpret_cast<float4*>(out + (size_t)(base + row) * DM + c4 * 4) =
            reinterpret_cast<const float4*>(bout)[c4];
      }
    }
  }

  if (pt >= n) return;

  float rc[3];
#pragma unroll
  for (int d = 0; d < 3; ++d) rc[d] = (float)(ws[3 + d] - ws[d]);

  unsigned int bits = 0u;
#pragma unroll
  for (int tt = 0; tt < NATT; ++tt) {
    bool m = true;
#pragma unroll
    for (int j = 0; j < 3; ++j) {
      // reference: ((logit * range_c) / 2).astype(int32)  (trunc toward 0)
      float off = acc[tt * 3 + j] * rc[j] * 0.5f;
      int oi = (int)off;
      m = m && (oi >= 0) && (oi < VOXC);
    }
    bits |= (m ? 1u : 0u) << tt;
  }
  if (bits) {
    int pos = atomicAdd(&ws[6], 1);
    ws[8 + pos] = pt;
    ws[8 + n + pos] = (int)bits;
  }
}

// For each active point: attn softmax, lazy value row, epilogue GEMM row add.
__global__ __launch_bounds__(64) void k_active(
    const float* __restrict__ q, const float* __restrict__ vfea,
    const int* __restrict__ coords,
    const float* __restrict__ Wattn, const float* __restrict__ battn,
    const float* __restrict__ Wval, const float* __restrict__ bval,
    const float* __restrict__ Wout,
    float* __restrict__ out, int n, const int* __restrict__ ws) {
  const int lane = threadIdx.x;  // block = 1 wave (64)
  const int count = ws[6];
  const int mn0 = ws[0], mn1 = ws[1], mn2 = ws[2];
  const float rv0 = (float)((ws[3] - mn0) / VOXC + 1);
  const float rv1 = (float)((ws[4] - mn1) / VOXC + 1);

  for (int i = blockIdx.x; i < count; i += gridDim.x) {
    int pt = ws[8 + i];
    unsigned int bits = (unsigned int)ws[8 + n + i];

    // gather row: exact in fp32 (all terms multiples of 1/8, < 2^24)
    float i0 = (float)(coords[pt * 3 + 0] - mn0) * 0.125f;
    float i1 = (float)(coords[pt * 3 + 1] - mn1) * 0.125f;
    float i2 = (float)(coords[pt * 3 + 2] - mn2) * 0.125f;
    float flat = i0 * rv1 * rv0 + i1 * rv0 + i2;
    int g = (int)floorf(flat);
    g = min(max(g, 0), n - 1);

    const float* qrow = q + (size_t)pt * DM;

    // attn logits + softmax on lanes 0..31 (lane t = h*4+p), grouped by 4
    float w_h = 0.0f;
    if (lane < NATT) {
      float acc = battn[lane];
      for (int k = 0; k < DM; ++k) acc = fmaf(qrow[k], Wattn[k * NATT + lane], acc);
      float m = acc;
      m = fmaxf(m, __shfl_xor(m, 1, 4));
      m = fmaxf(m, __shfl_xor(m, 2, 4));
      float e = expf(acc - m);
      float s = e;
      s += __shfl_xor(s, 1, 4);
      s += __shfl_xor(s, 2, 4);
      float a = e / s;
      float am = ((bits >> lane) & 1u) ? a : 0.0f;
      float w = am;
      w += __shfl_xor(w, 1, 4);
      w += __shfl_xor(w, 2, 4);
      w_h = w;  // valid on all 4 lanes of each head group
    }

    // lazy value row g: lane handles dims (lane, lane+64)
    const float* vrow = vfea + (size_t)g * DM;
    float v0 = bval[lane], v1 = bval[lane + 64];
    for (int k = 0; k < DM; ++k) {
      float f = vrow[k];
      v0 = fmaf(f, Wval[k * DM + lane], v0);
      v1 = fmaf(f, Wval[k * DM + lane + 64], v1);
    }
    float wh0 = __shfl(w_h, (lane >> 4) * 4, 64);        // head of dim = lane
    float wh1 = __shfl(w_h, ((lane >> 4) + 4) * 4, 64);  // head of dim = lane+64
    float o0 = wh0 * v0;
    float o1 = wh1 * v1;

    // row epilogue: out[pt,:] += o @ W_out   (out already holds b_out)
    float s0 = 0.0f, s1 = 0.0f;
    for (int d = 0; d < 64; ++d) {
      float od = __shfl(o0, d, 64);
      s0 = fmaf(od, Wout[d * DM + lane], s0);
      s1 = fmaf(od, Wout[d * DM + lane + 64], s1);
    }
    for (int d = 0; d < 64; ++d) {
      float od = __shfl(o1, d, 64);
      s0 = fmaf(od, Wout[(d + 64) * DM + lane], s0);
      s1 = fmaf(od, Wout[(d + 64) * DM + lane + 64], s1);
    }
    out[(size_t)pt * DM + lane] += s0;
    out[(size_t)pt * DM + lane + 64] += s1;
  }
}

extern "C" void kernel_launch(void* const* d_in, const int* in_sizes, int n_in,
                              void* d_out, int out_size, void* d_ws, size_t ws_size,
                              hipStream_t stream) {
  const float* q     = (const float*)d_in[0];
  const float* vfea  = (const float*)d_in[1];
  const int*   coords= (const int*)d_in[2];
  const float* Woff  = (const float*)d_in[3];
  const float* boff  = (const float*)d_in[4];
  const float* Wattn = (const float*)d_in[5];
  const float* battn = (const float*)d_in[6];
  const float* Wval  = (const float*)d_in[7];
  const float* bval  = (const float*)d_in[8];
  const float* Wout  = (const float*)d_in[9];
  const float* bout  = (const float*)d_in[10];
  float* out = (float*)d_out;
  int n = in_sizes[0] / DM;
  int* ws = (int*)d_ws;

  k_init<<<1, 64, 0, stream>>>(ws);
  k_minmax<<<64, 256, 0, stream>>>(coords, n, ws);
  k_mask<<<(n + 255) / 256, 256, 0, stream>>>(q, Woff, boff, bout, out, n, ws);
  k_active<<<256, 64, 0, stream>>>(q, vfea, coords, Wattn, battn, Wval, bval, Wout, out, n, ws);
}

// Round 3
// 332.565 us; speedup vs baseline: 1.6997x; 1.5168x over previous
//
#include <hip/hip_runtime.h>
#include <cstdint>
#include <climits>

static constexpr int DM   = 128;   // d_model
static constexpr int NCOL = 96;    // off columns (8 heads * 4 pts * 3)
static constexpr int NATT = 32;
static constexpr int VOXC = 8;
static constexpr int NPB  = 64;    // points per k_screen block
static constexpr int CAP  = 32768; // candidate list cap
static constexpr float MARGIN = 3.0f;  // bf16 screen margin (~7.4 sigma)

// ws layout (ints):
static constexpr int OFF_B     = 8;                    // B frags, 24KB (6144 ints)
static constexpr int OFF_CAND  = OFF_B + 24 * 64 * 4;  // 6152: candidate pt ids
static constexpr int OFF_CBITS = OFF_CAND + CAP;       // 38920: candidate screen bits
static constexpr int OFF_FINAL = OFF_CBITS + CAP;      // 71688: confirmed pt ids
static constexpr int OFF_BITS  = OFF_FINAL + CAP;      // 104456: per-point exact bits [n]
// total = 104456 + 200000 = 304456 ints = 1.22 MB

typedef __attribute__((ext_vector_type(8))) short bf16x8;
typedef __attribute__((ext_vector_type(4))) float f32x4;

__device__ inline unsigned f2bf(float f) {  // fp32 -> bf16 bits, RNE
  unsigned u = __float_as_uint(f);
  return (u + 0x7fffu + ((u >> 16) & 1u)) >> 16;
}

// ws init + Woff -> bf16 MFMA B-fragment layout (B[k=quad*8+j][n=lane&15])
__global__ __launch_bounds__(256) void k_init(const float* __restrict__ Woff,
                                              int* __restrict__ ws) {
  int t = threadIdx.x;
  if (t < 3) { ws[t] = INT_MAX; ws[3 + t] = INT_MIN; }
  if (t == 6) ws[6] = 0;
  if (t == 7) ws[7] = 0;
  for (int idx = t; idx < 24 * 64; idx += 256) {
    int f = idx >> 6, l = idx & 63;
    int s = f / 6, u = f - 6 * s;          // kstep, ntile
    int quad = l >> 4, nn = l & 15;
    int col = u * 16 + nn;
    int k0 = s * 32 + quad * 8;
    int4 d;
    d.x = (int)((f2bf(Woff[(k0 + 1) * NCOL + col]) << 16) | f2bf(Woff[(k0 + 0) * NCOL + col]));
    d.y = (int)((f2bf(Woff[(k0 + 3) * NCOL + col]) << 16) | f2bf(Woff[(k0 + 2) * NCOL + col]));
    d.z = (int)((f2bf(Woff[(k0 + 5) * NCOL + col]) << 16) | f2bf(Woff[(k0 + 4) * NCOL + col]));
    d.w = (int)((f2bf(Woff[(k0 + 7) * NCOL + col]) << 16) | f2bf(Woff[(k0 + 6) * NCOL + col]));
    *reinterpret_cast<int4*>(ws + OFF_B + idx * 4) = d;
  }
}

__global__ __launch_bounds__(256) void k_minmax(const int* __restrict__ coords, int n,
                                                int* __restrict__ ws) {
  __shared__ int bmn[3], bmx[3];
  int t = threadIdx.x;
  if (t < 3) { bmn[t] = INT_MAX; bmx[t] = INT_MIN; }
  __syncthreads();
  int mn[3] = {INT_MAX, INT_MAX, INT_MAX};
  int mx[3] = {INT_MIN, INT_MIN, INT_MIN};
  for (int i = blockIdx.x * blockDim.x + t; i < n; i += gridDim.x * blockDim.x) {
#pragma unroll
    for (int d = 0; d < 3; ++d) {
      int v = coords[i * 3 + d];
      mn[d] = min(mn[d], v);
      mx[d] = max(mx[d], v);
    }
  }
#pragma unroll
  for (int d = 0; d < 3; ++d) {
    for (int off = 32; off > 0; off >>= 1) {
      mn[d] = min(mn[d], __shfl_xor(mn[d], off, 64));
      mx[d] = max(mx[d], __shfl_xor(mx[d], off, 64));
    }
  }
  if ((t & 63) == 0) {
#pragma unroll
    for (int d = 0; d < 3; ++d) {
      atomicMin(&bmn[d], mn[d]);
      atomicMax(&bmx[d], mx[d]);
    }
  }
  __syncthreads();
  if (t < 3) {
    atomicMin(&ws[t], bmn[t]);
    atomicMax(&ws[3 + t], bmx[t]);
  }
}

// bf16 MFMA screen: 64 points/block, 16/wave. Fuses b_out prefill + bits zeroing.
__global__ __launch_bounds__(256) void k_screen(
    const float* __restrict__ q, const float* __restrict__ boff,
    const float* __restrict__ bout, float* __restrict__ out,
    int n, int* __restrict__ ws) {
  __shared__ int4 bfr[24 * 64];        // 24 KB B fragments
  __shared__ float lg[4 * 16 * 100];   // 25.6 KB logits, row stride 100

  const int t = threadIdx.x;
  const int wave = t >> 6, lane = t & 63;
  const int base = blockIdx.x * NPB;
  int* bits = ws + OFF_BITS;

  for (int i = t; i < 24 * 64; i += 256)
    bfr[i] = reinterpret_cast<const int4*>(ws + OFF_B)[i];

  // prefill out rows with b_out (coalesced float4)
  {
    float4 bv = reinterpret_cast<const float4*>(bout)[t & 31];
    for (int r = t >> 5; r < NPB; r += 8) {
      int row = base + r;
      if (row < n) reinterpret_cast<float4*>(out + (size_t)row * DM)[t & 31] = bv;
    }
  }
  if (t < NPB && base + t < n) bits[base + t] = 0;

  const int m = lane & 15, quad = lane >> 4;
  const int prow = base + wave * 16 + m;
  const float4* qr = reinterpret_cast<const float4*>(q + (size_t)min(prow, n - 1) * DM);

  f32x4 acc[6];
#pragma unroll
  for (int u = 0; u < 6; ++u) {
    float bv = boff[u * 16 + m];       // acc init = b_off (D col = lane&15)
    acc[u] = (f32x4){bv, bv, bv, bv};
  }
  __syncthreads();

#pragma unroll
  for (int s = 0; s < 4; ++s) {
    float4 x = qr[s * 8 + quad * 2];         // A[m=lane&15][k=quad*8+j]
    float4 y = qr[s * 8 + quad * 2 + 1];
    bf16x8 a;
    a[0] = (short)f2bf(x.x); a[1] = (short)f2bf(x.y);
    a[2] = (short)f2bf(x.z); a[3] = (short)f2bf(x.w);
    a[4] = (short)f2bf(y.x); a[5] = (short)f2bf(y.y);
    a[6] = (short)f2bf(y.z); a[7] = (short)f2bf(y.w);
#pragma unroll
    for (int u = 0; u < 6; ++u) {
      bf16x8 b = *reinterpret_cast<const bf16x8*>(&bfr[(s * 6 + u) * 64 + lane]);
      acc[u] = __builtin_amdgcn_mfma_f32_16x16x32_bf16(a, b, acc[u], 0, 0, 0);
    }
  }

  // D layout: col = lane&15, row = quad*4 + reg
#pragma unroll
  for (int u = 0; u < 6; ++u)
#pragma unroll
    for (int r = 0; r < 4; ++r)
      lg[(wave * 16 + quad * 4 + r) * 100 + u * 16 + m] = acc[u][r];
  __syncthreads();

  // eval: 4 lanes per point, 8 triples each, screen with margin
  const float rcs[3] = {(float)(ws[3] - ws[0]) * 0.5f,
                        (float)(ws[4] - ws[1]) * 0.5f,
                        (float)(ws[5] - ws[2]) * 0.5f};
  const int pw = lane >> 2, qq = lane & 3;
  const int point = base + wave * 16 + pw;
  const float* lp = &lg[(wave * 16 + pw) * 100 + qq * 24];
  float v[24];
#pragma unroll
  for (int i = 0; i < 6; ++i) {
    float4 vv = reinterpret_cast<const float4*>(lp)[i];
    v[4 * i] = vv.x; v[4 * i + 1] = vv.y; v[4 * i + 2] = vv.z; v[4 * i + 3] = vv.w;
  }
  unsigned bits8 = 0;
#pragma unroll
  for (int tt = 0; tt < 8; ++tt) {
    bool ok = true;
#pragma unroll
    for (int j = 0; j < 3; ++j) {
      float off = v[tt * 3 + j] * rcs[j];
      ok = ok && (off > -1.0f - MARGIN) && (off < 8.0f + MARGIN);
    }
    bits8 |= (ok ? 1u : 0u) << tt;
  }
  unsigned full = bits8 << (qq * 8);
  full |= (unsigned)__shfl_xor((int)full, 1, 4);
  full |= (unsigned)__shfl_xor((int)full, 2, 4);
  if (qq == 0 && full && point < n) {
    int pos = atomicAdd(&ws[6], 1);
    if (pos < CAP) {
      ws[OFF_CAND + pos] = point;
      ws[OFF_CBITS + pos] = (int)full;
    }
  }
}

// Exact fp32 recheck of screened triples (bit-identical fma order to round-2 path).
__global__ __launch_bounds__(256) void k_recheck(
    const float* __restrict__ q, const float* __restrict__ Woff,
    const float* __restrict__ boff, int n, int* __restrict__ ws) {
  int C = min(ws[6], CAP);
  int* bits = ws + OFF_BITS;
  int stride = gridDim.x * blockDim.x;
  for (int idx = blockIdx.x * blockDim.x + threadIdx.x; idx < C * 32; idx += stride) {
    int cand = idx >> 5, tt = idx & 31;
    unsigned cb = (unsigned)ws[OFF_CBITS + cand];
    if (!((cb >> tt) & 1u)) continue;
    int pt = ws[OFF_CAND + cand];
    float a0 = boff[tt * 3 + 0], a1 = boff[tt * 3 + 1], a2 = boff[tt * 3 + 2];
    const float* qrow = q + (size_t)pt * DM;
    for (int k = 0; k < DM; ++k) {
      float qk = qrow[k];
      a0 = fmaf(qk, Woff[k * NCOL + tt * 3 + 0], a0);
      a1 = fmaf(qk, Woff[k * NCOL + tt * 3 + 1], a1);
      a2 = fmaf(qk, Woff[k * NCOL + tt * 3 + 2], a2);
    }
    float rc0 = (float)(ws[3] - ws[0]);
    float rc1 = (float)(ws[4] - ws[1]);
    float rc2 = (float)(ws[5] - ws[2]);
    int o0 = (int)(a0 * rc0 * 0.5f);
    int o1 = (int)(a1 * rc1 * 0.5f);
    int o2 = (int)(a2 * rc2 * 0.5f);
    if (o0 >= 0 && o0 < VOXC && o1 >= 0 && o1 < VOXC && o2 >= 0 && o2 < VOXC) {
      int old = atomicOr(&bits[pt], 1 << tt);
      if (old == 0) {
        int pos = atomicAdd(&ws[7], 1);
        if (pos < CAP) ws[OFF_FINAL + pos] = pt;
      }
    }
  }
}

// For each confirmed point: attn softmax, lazy value row, epilogue row add.
__global__ __launch_bounds__(64) void k_active(
    const float* __restrict__ q, const float* __restrict__ vfea,
    const int* __restrict__ coords,
    const float* __restrict__ Wattn, const float* __restrict__ battn,
    const float* __restrict__ Wval, const float* __restrict__ bval,
    const float* __restrict__ Wout,
    float* __restrict__ out, int n, const int* __restrict__ ws) {
  const int lane = threadIdx.x;  // block = 1 wave
  const int count = min(ws[7], CAP);
  const int mn0 = ws[0], mn1 = ws[1], mn2 = ws[2];
  const float rv0 = (float)((ws[3] - mn0) / VOXC + 1);
  const float rv1 = (float)((ws[4] - mn1) / VOXC + 1);
  const int* bits_arr = ws + OFF_BITS;

  for (int i = blockIdx.x; i < count; i += gridDim.x) {
    int pt = ws[OFF_FINAL + i];
    unsigned int bits = (unsigned int)bits_arr[pt];

    float i0 = (float)(coords[pt * 3 + 0] - mn0) * 0.125f;
    float i1 = (float)(coords[pt * 3 + 1] - mn1) * 0.125f;
    float i2 = (float)(coords[pt * 3 + 2] - mn2) * 0.125f;
    float flat = i0 * rv1 * rv0 + i1 * rv0 + i2;
    int g = (int)floorf(flat);
    g = min(max(g, 0), n - 1);

    const float* qrow = q + (size_t)pt * DM;

    float w_h = 0.0f;
    if (lane < NATT) {
      float acc = battn[lane];
      for (int k = 0; k < DM; ++k) acc = fmaf(qrow[k], Wattn[k * NATT + lane], acc);
      float mx = acc;
      mx = fmaxf(mx, __shfl_xor(mx, 1, 4));
      mx = fmaxf(mx, __shfl_xor(mx, 2, 4));
      float e = expf(acc - mx);
      float s = e;
      s += __shfl_xor(s, 1, 4);
      s += __shfl_xor(s, 2, 4);
      float a = e / s;
      float am = ((bits >> lane) & 1u) ? a : 0.0f;
      float w = am;
      w += __shfl_xor(w, 1, 4);
      w += __shfl_xor(w, 2, 4);
      w_h = w;
    }

    const float* vrow = vfea + (size_t)g * DM;
    float v0 = bval[lane], v1 = bval[lane + 64];
    for (int k = 0; k < DM; ++k) {
      float f = vrow[k];
      v0 = fmaf(f, Wval[k * DM + lane], v0);
      v1 = fmaf(f, Wval[k * DM + lane + 64], v1);
    }
    float wh0 = __shfl(w_h, (lane >> 4) * 4, 64);
    float wh1 = __shfl(w_h, ((lane >> 4) + 4) * 4, 64);
    float o0 = wh0 * v0;
    float o1 = wh1 * v1;

    float s0 = 0.0f, s1 = 0.0f;
    for (int d = 0; d < 64; ++d) {
      float od = __shfl(o0, d, 64);
      s0 = fmaf(od, Wout[d * DM + lane], s0);
      s1 = fmaf(od, Wout[d * DM + lane + 64], s1);
    }
    for (int d = 0; d < 64; ++d) {
      float od = __shfl(o1, d, 64);
      s0 = fmaf(od, Wout[(d + 64) * DM + lane], s0);
      s1 = fmaf(od, Wout[(d + 64) * DM + lane + 64], s1);
    }
    out[(size_t)pt * DM + lane] += s0;
    out[(size_t)pt * DM + lane + 64] += s1;
  }
}

extern "C" void kernel_launch(void* const* d_in, const int* in_sizes, int n_in,
                              void* d_out, int out_size, void* d_ws, size_t ws_size,
                              hipStream_t stream) {
  const float* q     = (const float*)d_in[0];
  const float* vfea  = (const float*)d_in[1];
  const int*   coords= (const int*)d_in[2];
  const float* Woff  = (const float*)d_in[3];
  const float* boff  = (const float*)d_in[4];
  const float* Wattn = (const float*)d_in[5];
  const float* battn = (const float*)d_in[6];
  const float* Wval  = (const float*)d_in[7];
  const float* bval  = (const float*)d_in[8];
  const float* Wout  = (const float*)d_in[9];
  const float* bout  = (const float*)d_in[10];
  float* out = (float*)d_out;
  int n = in_sizes[0] / DM;
  int* ws = (int*)d_ws;

  k_init<<<1, 256, 0, stream>>>(Woff, ws);
  k_minmax<<<64, 256, 0, stream>>>(coords, n, ws);
  k_screen<<<(n + NPB - 1) / NPB, 256, 0, stream>>>(q, boff, bout, out, n, ws);
  k_recheck<<<64, 256, 0, stream>>>(q, Woff, boff, n, ws);
  k_active<<<256, 64, 0, stream>>>(q, vfea, coords, Wattn, battn, Wval, bval, Wout, out, n, ws);
}

// Round 4
// 314.228 us; speedup vs baseline: 1.7989x; 1.0584x over previous
//
#include <hip/hip_runtime.h>
#include <cstdint>
#include <climits>

static constexpr int DM   = 128;   // d_model
static constexpr int NCOL = 96;    // off columns
static constexpr int NATT = 32;
static constexpr int VOXC = 8;
static constexpr int CAP  = 32768;
static constexpr float MARGIN = 4.0f;  // screen margin in off-units (~13 sigma)

// ws layout (ints):
static constexpr int OFF_B     = 8;                   // B frags 24KB (6144 ints)
static constexpr int OFF_BP    = OFF_B + 24 * 64 * 4; // 6152: permuted b_off (96 floats)
static constexpr int OFF_CAND  = OFF_BP + 96;         // 6248: candidate pt ids
static constexpr int OFF_FINAL = OFF_CAND + CAP;      // 39016: confirmed pt ids
static constexpr int OFF_BITS  = OFF_FINAL + CAP;     // 71784: exact bits per confirmed pt [n]

typedef __attribute__((ext_vector_type(8))) short bf16x8;
typedef __attribute__((ext_vector_type(4))) float f32x4;

__device__ inline unsigned f2bf_rne(float f) {  // fp32 -> bf16 bits, RNE
  unsigned u = __float_as_uint(f);
  return (u + 0x7fffu + ((u >> 16) & 1u)) >> 16;
}
// column permutation: tile u (0..5), frag col nn (0..15) <- original Woff col.
// dim j = u>>1 of triple t = (u&1)*16 + nn  ->  orig col = t*3 + j
__device__ inline int colperm(int u, int nn) {
  return ((u & 1) * 16 + nn) * 3 + (u >> 1);
}

__global__ __launch_bounds__(256) void k_init(const float* __restrict__ Woff,
                                              const float* __restrict__ boff,
                                              int* __restrict__ ws) {
  int t = threadIdx.x;
  if (blockIdx.x == 0) {
    if (t < 3) { ws[t] = INT_MAX; ws[3 + t] = INT_MIN; }
    if (t == 6) ws[6] = 0;
    if (t == 7) ws[7] = 0;
    if (t < 96)
      reinterpret_cast<float*>(ws + OFF_BP)[t] = boff[colperm(t >> 4, t & 15)];
  }
  int idx = blockIdx.x * 256 + t;
  if (idx < 24 * 64) {
    int f = idx >> 6, l = idx & 63;
    int s = f / 6, u = f - 6 * s;       // kstep, ntile
    int quad = l >> 4, nn = l & 15;
    int col = colperm(u, nn);
    int k0 = s * 32 + quad * 8;
    int4 d;
    d.x = (int)((f2bf_rne(Woff[(k0 + 1) * NCOL + col]) << 16) | f2bf_rne(Woff[(k0 + 0) * NCOL + col]));
    d.y = (int)((f2bf_rne(Woff[(k0 + 3) * NCOL + col]) << 16) | f2bf_rne(Woff[(k0 + 2) * NCOL + col]));
    d.z = (int)((f2bf_rne(Woff[(k0 + 5) * NCOL + col]) << 16) | f2bf_rne(Woff[(k0 + 4) * NCOL + col]));
    d.w = (int)((f2bf_rne(Woff[(k0 + 7) * NCOL + col]) << 16) | f2bf_rne(Woff[(k0 + 6) * NCOL + col]));
    *reinterpret_cast<int4*>(ws + OFF_B + idx * 4) = d;
  }
}

__global__ __launch_bounds__(256) void k_minmax(const int* __restrict__ coords, int n,
                                                int* __restrict__ ws) {
  __shared__ int bmn[3], bmx[3];
  int t = threadIdx.x;
  if (t < 3) { bmn[t] = INT_MAX; bmx[t] = INT_MIN; }
  __syncthreads();
  int mn[3] = {INT_MAX, INT_MAX, INT_MAX};
  int mx[3] = {INT_MIN, INT_MIN, INT_MIN};
  for (int i = blockIdx.x * blockDim.x + t; i < n; i += gridDim.x * blockDim.x) {
#pragma unroll
    for (int d = 0; d < 3; ++d) {
      int v = coords[i * 3 + d];
      mn[d] = min(mn[d], v);
      mx[d] = max(mx[d], v);
    }
  }
#pragma unroll
  for (int d = 0; d < 3; ++d) {
    for (int off = 32; off > 0; off >>= 1) {
      mn[d] = min(mn[d], __shfl_xor(mn[d], off, 64));
      mx[d] = max(mx[d], __shfl_xor(mx[d], off, 64));
    }
  }
  if ((t & 63) == 0) {
#pragma unroll
    for (int d = 0; d < 3; ++d) {
      atomicMin(&bmn[d], mn[d]);
      atomicMax(&bmx[d], mx[d]);
    }
  }
  __syncthreads();
  if (t < 3) {
    atomicMin(&ws[t], bmn[t]);
    atomicMax(&ws[3 + t], bmx[t]);
  }
}

// bf16 MFMA point-screen: 64 pts/block (16/wave). In-lane triple-AND via column
// permutation; emits candidate POINT ids only. Fuses b_out prefill.
__global__ __launch_bounds__(256, 4) void k_screen(
    const float* __restrict__ q, const float* __restrict__ bout,
    float* __restrict__ out, int n, int* __restrict__ ws) {
  __shared__ int4 bfr[24 * 64];  // 24 KB B fragments

  const int t = threadIdx.x;
  const int wave = t >> 6, lane = t & 63;
  const int base = blockIdx.x * 64;

  for (int i = t; i < 24 * 64; i += 256)
    bfr[i] = reinterpret_cast<const int4*>(ws + OFF_B)[i];

  // prefill out rows with b_out (coalesced float4); i & 31 == t & 31 always
  {
    float4 bv = reinterpret_cast<const float4*>(bout)[t & 31];
    for (int i = t; i < 64 * 32; i += 256) {
      int row = base + (i >> 5);
      if (row < n) reinterpret_cast<float4*>(out)[(size_t)row * 32 + (i & 31)] = bv;
    }
  }

  const int m = lane & 15, quad = lane >> 4;
  const int prow = base + wave * 16 + m;
  const float4* qr = reinterpret_cast<const float4*>(q + (size_t)min(prow, n - 1) * DM);
  const float* bp = reinterpret_cast<const float*>(ws + OFF_BP);

  f32x4 acc[6];
#pragma unroll
  for (int u = 0; u < 6; ++u) {
    float bv = bp[u * 16 + m];
    acc[u] = (f32x4){bv, bv, bv, bv};
  }
  __syncthreads();

#pragma unroll
  for (int s = 0; s < 4; ++s) {
    float4 x = qr[s * 8 + quad * 2];      // A[m=lane&15][k=quad*8+j]
    float4 y = qr[s * 8 + quad * 2 + 1];
    union { int4 i; bf16x8 h; } A;        // truncation pack (hi16), margin covers it
    A.i.x = (int)((__float_as_uint(x.y) & 0xffff0000u) | (__float_as_uint(x.x) >> 16));
    A.i.y = (int)((__float_as_uint(x.w) & 0xffff0000u) | (__float_as_uint(x.z) >> 16));
    A.i.z = (int)((__float_as_uint(y.y) & 0xffff0000u) | (__float_as_uint(y.x) >> 16));
    A.i.w = (int)((__float_as_uint(y.w) & 0xffff0000u) | (__float_as_uint(y.z) >> 16));
#pragma unroll
    for (int u = 0; u < 6; ++u) {
      union { int4 i; bf16x8 h; } B;
      B.i = bfr[(s * 6 + u) * 64 + lane];
      acc[u] = __builtin_amdgcn_mfma_f32_16x16x32_bf16(A.h, B.h, acc[u], 0, 0, 0);
    }
  }

  // eval: D row = quad*4+r, col = u*16+m. Triple t=(u&1)*16+m, dims in u={g,2+g,4+g}.
  const float rcs[3] = {(float)(ws[3] - ws[0]) * 0.5f,
                        (float)(ws[4] - ws[1]) * 0.5f,
                        (float)(ws[5] - ws[2]) * 0.5f};
  unsigned long long b[4];
#pragma unroll
  for (int r = 0; r < 4; ++r) {
    bool any = false;
#pragma unroll
    for (int g = 0; g < 2; ++g) {
      bool ok = true;
#pragma unroll
      for (int j = 0; j < 3; ++j) {
        float off = acc[2 * j + g][r] * rcs[j];
        ok = ok && (off > -1.0f - MARGIN) && (off < 8.0f + MARGIN);
      }
      any = any || ok;
    }
    b[r] = __ballot(any);
  }
  if (lane < 16) {
    int p = lane;
    int point = base + wave * 16 + p;
    unsigned long long bb = (p & 1) ? ((p & 2) ? b[3] : b[1])
                                    : ((p & 2) ? b[2] : b[0]);
    if (point < n && ((bb >> ((p >> 2) * 16)) & 0xffffull)) {
      int pos = atomicAdd(&ws[6], 1);
      if (pos < CAP) ws[OFF_CAND + pos] = point;
    }
  }
}

// Exact fp32 recheck: all 96 logits per candidate point (same fma order as the
// reference-matched path), builds the exact 32-bit triple mask + final list.
__global__ __launch_bounds__(128) void k_recheck(
    const float* __restrict__ q, const float* __restrict__ Woff,
    const float* __restrict__ boff, int n, int* __restrict__ ws) {
  __shared__ int ok[96];
  const int t = threadIdx.x;
  const int C = min(ws[6], CAP);
  const float rc[3] = {(float)(ws[3] - ws[0]), (float)(ws[4] - ws[1]),
                       (float)(ws[5] - ws[2])};
  int* bits = ws + OFF_BITS;
  for (int i = blockIdx.x; i < C; i += gridDim.x) {
    int pt = ws[OFF_CAND + i];
    const float* qrow = q + (size_t)pt * DM;
    if (t < 96) {
      float a = boff[t];
      for (int k = 0; k < DM; ++k) a = fmaf(qrow[k], Woff[k * NCOL + t], a);
      int oi = (int)(a * rc[t % 3] * 0.5f);
      ok[t] = (oi >= 0) && (oi < VOXC);
    }
    __syncthreads();
    if (t < 32) {
      bool mt = ok[3 * t] && ok[3 * t + 1] && ok[3 * t + 2];
      unsigned long long bb = __ballot(mt);
      if (t == 0) {
        unsigned bits32 = (unsigned)bb;
        if (bits32) {
          bits[pt] = (int)bits32;
          int pos = atomicAdd(&ws[7], 1);
          if (pos < CAP) ws[OFF_FINAL + pos] = pt;
        }
      }
    }
    __syncthreads();
  }
}

// For each confirmed point: attn softmax, lazy value row, epilogue row add.
__global__ __launch_bounds__(64) void k_active(
    const float* __restrict__ q, const float* __restrict__ vfea,
    const int* __restrict__ coords,
    const float* __restrict__ Wattn, const float* __restrict__ battn,
    const float* __restrict__ Wval, const float* __restrict__ bval,
    const float* __restrict__ Wout,
    float* __restrict__ out, int n, const int* __restrict__ ws) {
  const int lane = threadIdx.x;  // block = 1 wave
  const int count = min(ws[7], CAP);
  const int mn0 = ws[0], mn1 = ws[1], mn2 = ws[2];
  const float rv0 = (float)((ws[3] - mn0) / VOXC + 1);
  const float rv1 = (float)((ws[4] - mn1) / VOXC + 1);
  const int* bits_arr = ws + OFF_BITS;

  for (int i = blockIdx.x; i < count; i += gridDim.x) {
    int pt = ws[OFF_FINAL + i];
    unsigned int bits = (unsigned int)bits_arr[pt];

    float i0 = (float)(coords[pt * 3 + 0] - mn0) * 0.125f;
    float i1 = (float)(coords[pt * 3 + 1] - mn1) * 0.125f;
    float i2 = (float)(coords[pt * 3 + 2] - mn2) * 0.125f;
    float flat = i0 * rv1 * rv0 + i1 * rv0 + i2;
    int g = (int)floorf(flat);
    g = min(max(g, 0), n - 1);

    const float* qrow = q + (size_t)pt * DM;

    float w_h = 0.0f;
    if (lane < NATT) {
      float acc = battn[lane];
      for (int k = 0; k < DM; ++k) acc = fmaf(qrow[k], Wattn[k * NATT + lane], acc);
      float mx = acc;
      mx = fmaxf(mx, __shfl_xor(mx, 1, 4));
      mx = fmaxf(mx, __shfl_xor(mx, 2, 4));
      float e = expf(acc - mx);
      float s = e;
      s += __shfl_xor(s, 1, 4);
      s += __shfl_xor(s, 2, 4);
      float a = e / s;
      float am = ((bits >> lane) & 1u) ? a : 0.0f;
      float w = am;
      w += __shfl_xor(w, 1, 4);
      w += __shfl_xor(w, 2, 4);
      w_h = w;
    }

    const float* vrow = vfea + (size_t)g * DM;
    float v0 = bval[lane], v1 = bval[lane + 64];
    for (int k = 0; k < DM; ++k) {
      float f = vrow[k];
      v0 = fmaf(f, Wval[k * DM + lane], v0);
      v1 = fmaf(f, Wval[k * DM + lane + 64], v1);
    }
    float wh0 = __shfl(w_h, (lane >> 4) * 4, 64);
    float wh1 = __shfl(w_h, ((lane >> 4) + 4) * 4, 64);
    float o0 = wh0 * v0;
    float o1 = wh1 * v1;

    float s0 = 0.0f, s1 = 0.0f;
    for (int d = 0; d < 64; ++d) {
      float od = __shfl(o0, d, 64);
      s0 = fmaf(od, Wout[d * DM + lane], s0);
      s1 = fmaf(od, Wout[d * DM + lane + 64], s1);
    }
    for (int d = 0; d < 64; ++d) {
      float od = __shfl(o1, d, 64);
      s0 = fmaf(od, Wout[(d + 64) * DM + lane], s0);
      s1 = fmaf(od, Wout[(d + 64) * DM + lane + 64], s1);
    }
    out[(size_t)pt * DM + lane] += s0;
    out[(size_t)pt * DM + lane + 64] += s1;
  }
}

extern "C" void kernel_launch(void* const* d_in, const int* in_sizes, int n_in,
                              void* d_out, int out_size, void* d_ws, size_t ws_size,
                              hipStream_t stream) {
  const float* q     = (const float*)d_in[0];
  const float* vfea  = (const float*)d_in[1];
  const int*   coords= (const int*)d_in[2];
  const float* Woff  = (const float*)d_in[3];
  const float* boff  = (const float*)d_in[4];
  const float* Wattn = (const float*)d_in[5];
  const float* battn = (const float*)d_in[6];
  const float* Wval  = (const float*)d_in[7];
  const float* bval  = (const float*)d_in[8];
  const float* Wout  = (const float*)d_in[9];
  const float* bout  = (const float*)d_in[10];
  float* out = (float*)d_out;
  int n = in_sizes[0] / DM;
  int* ws = (int*)d_ws;

  k_init<<<8, 256, 0, stream>>>(Woff, boff, ws);
  k_minmax<<<64, 256, 0, stream>>>(coords, n, ws);
  k_screen<<<(n + 63) / 64, 256, 0, stream>>>(q, bout, out, n, ws);
  k_recheck<<<512, 128, 0, stream>>>(q, Woff, boff, n, ws);
  k_active<<<256, 64, 0, stream>>>(q, vfea, coords, Wattn, battn, Wval, bval, Wout, out, n, ws);
}